// Round 21
// baseline (30.615 us; speedup 1.0000x reference)
//
#include <hip/hip_runtime.h>
#include <hip/hip_bf16.h>

// PseudoTripletLoss on MI355X (gfx950)
// loss*n(n-1) = sum_{i<j} relu(s-0.1)                 [GEMM blocks, label-blind]
//             + sum_{i<j,same} ((1-s) - relu(s-0.1))  [corr blocks, same dispatch, FIRST]
// R21: production kernel = R17's measured-fast ablation config (10.2us/pass):
//  512-thread blocks, 33 KB LDS ONLY (A bounced through the 2 B-buffers; no
//  dedicated Abuf), (512,4) -> ~4 blocks/CU (32 waves/CU) instead of the 2
//  blocks/CU (66 KB) every "real" kernel has run at since R6. Occupancy was
//  the 2x. Corr blocks share the dispatch (lead it) and reuse buf as their
//  128x128 tile, keeping LDS at 33 KB.

typedef __attribute__((ext_vector_type(8))) short short8;
typedef __attribute__((ext_vector_type(4))) float f32x4;

#define DIM 128
#define MARGIN 0.1f
#define CHUNK 4
#define NLAB 100
#define CAP 128

typedef const void __attribute__((address_space(1)))* gas_ptr;
typedef void __attribute__((address_space(3)))* las_ptr;

static __device__ __forceinline__ void load16_to_lds(const void* g, void* l) {
    __builtin_amdgcn_global_load_lds((gas_ptr)g, (las_ptr)l, 16, 0, 0);
}

static __device__ __forceinline__ unsigned short f2bf(float f) {
    unsigned int u = __builtin_bit_cast(unsigned int, f);
    u += 0x7FFFu + ((u >> 16) & 1u);
    return (unsigned short)(u >> 16);
}

// 512-thread staging of a 64x128 bf16 tile; lane-linear LDS dest; XOR
// involution on the SOURCE column.
static __device__ __forceinline__ void stage64(const short* __restrict__ en, int row0,
                                               short* buf, int tid) {
    const char* src = (const char*)(en + (size_t)row0 * DIM);
    char* dst = (char*)buf;
    const int r_lo = tid >> 4;       // 0..31
    const int s    = tid & 15;
    #pragma unroll
    for (int p = 0; p < 2; ++p) {
        const int r  = p * 32 + r_lo;
        const int sc = (s ^ (r & 7)) << 4;
        load16_to_lds(src + (size_t)r * 256 + sc, dst + r * 256 + s * 16);
    }
}

static __device__ __forceinline__ short8 read_frag(const short* buf, int row, int slot) {
    const int ps = slot ^ (row & 7);
    return *(const short8*)(buf + row * DIM + ps * 8);
}

// ---------------- K1: normalize rows -> packed bf16 (non-temporal stores) ----------------
__global__ void __launch_bounds__(256) norm_bf16_kernel(const float* __restrict__ e,
                                                        unsigned int* __restrict__ en_packed) {
    const int row  = blockIdx.x * 4 + (threadIdx.x >> 6);
    const int lane = threadIdx.x & 63;
    const float2 v = *reinterpret_cast<const float2*>(e + row * DIM + lane * 2);
    float s = v.x * v.x + v.y * v.y;
    #pragma unroll
    for (int off = 32; off; off >>= 1) s += __shfl_xor(s, off, 64);
    const float scale = 1.0f / fmaxf(sqrtf(s), 1e-8f);
    const unsigned int lo = f2bf(v.x * scale);
    const unsigned int hi = f2bf(v.y * scale);
    __builtin_nontemporal_store((hi << 16) | lo, &en_packed[row * (DIM / 2) + lane]);
}

// ---------------- fused kernel: corr blocks (< NLAB) then GEMM blocks ----------------
__global__ void __launch_bounds__(512, 4)
fused_kernel(const short* __restrict__ en, const int* __restrict__ labels, int n,
             float* __restrict__ partials, int nt) {
    __shared__ __align__(16) short buf[2][64 * DIM];   // 32 KB total — the ONLY big LDS
    __shared__ float wsum[8];
    __shared__ int list[CAP];
    __shared__ int ccnt;

    const int tid  = threadIdx.x;
    const int lane = tid & 63;
    const int wid  = tid >> 6;          // 8 waves
    const int lm   = lane & 15;
    const int hi   = lane >> 4;
    const int rb   = hi * 4;

    if ((int)blockIdx.x < NLAB) {
        // ================= corr block: class c (leads the grid, overlaps GEMM) ==========
        const int c = (int)blockIdx.x;
        if (tid == 0) ccnt = 0;
        __syncthreads();
        #pragma unroll 1
        for (int it = 0; it < n / 512; ++it) {       // 16 coalesced iterations
            const int i = it * 512 + tid;
            if (labels[i] == c) {
                const int p = atomicAdd(&ccnt, 1);   // order-free: pair set invariant
                if (p < CAP) list[p] = i;
            }
        }
        __syncthreads();
        const int nc = min(ccnt, CAP);

        float csum = 0.0f;
        short* tile = &buf[0][0];                    // 128 x 128 gather tile (32 KB)
        if (nc > 1) {
            {
                const int rlo = tid >> 4, sl = tid & 15;
                #pragma unroll
                for (int p = 0; p < 4; ++p) {
                    const int r    = p * 32 + rlo;
                    const int srow = list[r < nc ? r : 0];
                    const int sc   = (sl ^ (r & 7)) << 4;
                    load16_to_lds((const char*)en + (size_t)srow * 256 + sc,
                                  (char*)tile + r * 256 + sl * 16);
                }
            }
            __syncthreads();

            const int wr = wid >> 1;      // 0..3: 32-row band
            const int wc = wid & 1;       // 0..1: 64-col half
            short8 a[2][4];
            #pragma unroll
            for (int m = 0; m < 2; ++m)
                #pragma unroll
                for (int ks = 0; ks < 4; ++ks)
                    a[m][ks] = read_frag(tile, wr * 32 + m * 16 + lm, hi + ks * 4);

            f32x4 acc[2][4] = {};
            #pragma unroll
            for (int ks = 0; ks < 4; ++ks) {
                short8 b[4];
                #pragma unroll
                for (int nn = 0; nn < 4; ++nn)
                    b[nn] = read_frag(tile, wc * 64 + nn * 16 + lm, hi + ks * 4);
                #pragma unroll
                for (int m = 0; m < 2; ++m)
                    #pragma unroll
                    for (int nn = 0; nn < 4; ++nn)
                        acc[m][nn] = __builtin_amdgcn_mfma_f32_16x16x32_bf16(a[m][ks], b[nn], acc[m][nn], 0, 0, 0);
            }

            #pragma unroll
            for (int m = 0; m < 2; ++m)
                #pragma unroll
                for (int nn = 0; nn < 4; ++nn) {
                    const int v = wc * 64 + nn * 16 + lm;
                    #pragma unroll
                    for (int r = 0; r < 4; ++r) {
                        const int u = wr * 32 + m * 16 + rb + r;
                        const float s = acc[m][nn][r];
                        const float t = (1.0f - s) - fmaxf(s - MARGIN, 0.0f);
                        csum += (u < v && v < nc) ? t : 0.0f;
                    }
                }
        } else {
            __syncthreads();   // uniform barrier count
        }

        #pragma unroll
        for (int o = 32; o; o >>= 1) csum += __shfl_down(csum, o, 64);
        if (lane == 0) wsum[wid] = csum;
        __syncthreads();
        if (tid == 0) {
            float b = 0.0f;
            #pragma unroll
            for (int w = 0; w < 8; ++w) b += wsum[w];
            partials[blockIdx.x] = b;
        }
        return;
    }

    // ================= GEMM block (label-blind) — exact R17-ablation structure ==========
    int t  = (int)blockIdx.x - NLAB;
    int bi = 0, cnt = (nt + CHUNK - 1) / CHUNK;
    #pragma unroll 1
    while (t >= cnt) { t -= cnt; ++bi; cnt = (nt - bi + CHUNK - 1) / CHUNK; }
    const int jbase = bi + t * CHUNK;
    const int jb128 = jbase * 128;
    const int nsub  = 2 * min(CHUNK, nt - jbase);

    const int wr = wid >> 1;            // 0..3: 32-row band
    const int wc = wid & 1;             // 0..1: 32-col half

    // prologue: A strip bounced through the two B buffers (keeps LDS at 33 KB)
    stage64(en, bi * 128,      &buf[0][0], tid);
    stage64(en, bi * 128 + 64, &buf[1][0], tid);
    const int r0w = bi * 128 + wr * 32;
    __syncthreads();                    // A staged

    short8 a[2][4];
    const short* Abuf = &buf[wr >> 1][0];
    const int rloc = (wr & 1) * 32;
    #pragma unroll
    for (int m = 0; m < 2; ++m)
        #pragma unroll
        for (int ks = 0; ks < 4; ++ks)
            a[m][ks] = read_frag(Abuf, rloc + m * 16 + lm, hi + ks * 4);
    __syncthreads();                    // A reads done -> bufs reusable

    stage64(en, jb128, &buf[0][0], tid);   // first B subtile
    __syncthreads();                    // B0 staged

    f32x4 vsum = (f32x4){0.0f, 0.0f, 0.0f, 0.0f};
    #pragma unroll 1
    for (int s = 0; s < nsub; ++s) {
        const short* cur = &buf[s & 1][0];
        if (s + 1 < nsub)
            stage64(en, jb128 + (s + 1) * 64, &buf[(s + 1) & 1][0], tid);

        f32x4 acc[2][2] = {};
        #pragma unroll
        for (int ks = 0; ks < 4; ++ks) {
            short8 b[2];
            b[0] = read_frag(cur, wc * 32 + lm,      hi + ks * 4);
            b[1] = read_frag(cur, wc * 32 + 16 + lm, hi + ks * 4);
            #pragma unroll
            for (int m = 0; m < 2; ++m)
                #pragma unroll
                for (int n = 0; n < 2; ++n)
                    acc[m][n] = __builtin_amdgcn_mfma_f32_16x16x32_bf16(a[m][ks], b[n], acc[m][n], 0, 0, 0);
        }

        // label-blind epilogue: 3 ops/elem
        if ((jbase == bi) && (s < 2)) {            // diagonal subtile: strict i<j
            const int c0 = jb128 + s * 64 + wc * 32;
            #pragma unroll
            for (int m = 0; m < 2; ++m)
                #pragma unroll
                for (int n = 0; n < 2; ++n) {
                    const f32x4 sv = acc[m][n] - MARGIN;
                    const int jj = c0 + n * 16 + lm;
                    #pragma unroll
                    for (int r = 0; r < 4; ++r) {
                        const int ii = r0w + m * 16 + rb + r;
                        vsum[r] += (ii < jj) ? fmaxf(sv[r], 0.0f) : 0.0f;
                    }
                }
        } else {
            #pragma unroll
            for (int m = 0; m < 2; ++m)
                #pragma unroll
                for (int n = 0; n < 2; ++n) {
                    const f32x4 sv = acc[m][n] - MARGIN;
                    #pragma unroll
                    for (int r = 0; r < 4; ++r)
                        vsum[r] += fmaxf(sv[r], 0.0f);
                }
        }
        __syncthreads();   // drains stage(s+1) + all reads of buf[s&1]
    }

    float lsum = vsum[0] + vsum[1] + vsum[2] + vsum[3];
    #pragma unroll
    for (int off = 32; off; off >>= 1) lsum += __shfl_down(lsum, off, 64);
    if (lane == 0) wsum[wid] = lsum;
    __syncthreads();
    if (tid == 0) {
        float b = 0.0f;
        #pragma unroll
        for (int w = 0; w < 8; ++w) b += wsum[w];
        partials[blockIdx.x] = b;
    }
}

// ---------------- K3: final deterministic reduce ----------------
__global__ void __launch_bounds__(256) final_reduce_kernel(const float* __restrict__ partials,
                                                           float* __restrict__ out,
                                                           int n, float inv_denom) {
    float s = 0.0f;
    for (int i = threadIdx.x; i < n; i += 256) s += partials[i];
    #pragma unroll
    for (int off = 32; off; off >>= 1) s += __shfl_xor(s, off, 64);
    __shared__ float wsum[4];
    if ((threadIdx.x & 63) == 0) wsum[threadIdx.x >> 6] = s;
    __syncthreads();
    if (threadIdx.x == 0) out[0] = (wsum[0] + wsum[1] + wsum[2] + wsum[3]) * inv_denom;
}

extern "C" void kernel_launch(void* const* d_in, const int* in_sizes, int n_in,
                              void* d_out, int out_size, void* d_ws, size_t ws_size,
                              hipStream_t stream) {
    const float* emb    = (const float*)d_in[0];
    const int*   labels = (const int*)d_in[1];
    float*       out    = (float*)d_out;

    const int n  = in_sizes[1];      // 8192
    const int nt = n / 128;          // 64 strips

    int Tc = 0;                      // 544 GEMM blocks at CHUNK=4
    for (int i = 0; i < nt; ++i) Tc += (nt - i + CHUNK - 1) / CHUNK;

    unsigned int* en_packed = (unsigned int*)d_ws;
    short*        en        = (short*)d_ws;
    float*        partials  = (float*)((char*)d_ws + (size_t)n * DIM * 2);  // NLAB+Tc

    norm_bf16_kernel<<<n / 4, 256, 0, stream>>>(emb, en_packed);

    fused_kernel<<<NLAB + Tc, 512, 0, stream>>>(en, labels, n, partials, nt);

    const float inv_denom = (float)(1.0 / ((double)n * (double)(n - 1)));
    final_reduce_kernel<<<1, 256, 0, stream>>>(partials, out, NLAB + Tc, inv_denom);
}